// Round 9
// baseline (1406.992 us; speedup 1.0000x reference)
//
#include <hip/hip_runtime.h>
#include <hip/hip_bf16.h>
#include <math.h>

// Problem constants
#define NSL 8000
#define MPAD 8064          // 63 * 128
#define EDIM 512
#define DI_ 1024
#define SDIM 16
#define NLAY 2
#define CHK 500
#define PSEG 10
#define LSEG 50

typedef __bf16 bf16_t;
typedef bf16_t bf16x8 __attribute__((ext_vector_type(8)));
typedef bf16_t bf16x4 __attribute__((ext_vector_type(4)));
typedef float  f32x4  __attribute__((ext_vector_type(4)));

#define GL2LDS(g, l) __builtin_amdgcn_global_load_lds( \
    (const __attribute__((address_space(1))) void*)(g), \
    (__attribute__((address_space(3))) void*)(l), 16, 0, 0)

// ================= split-bf16 MFMA GEMM: C = A*W^T (+epilogue) =================
// A_hi/A_lo: [MPAD][K] bf16 row-major, fragments loaded DIRECT global->reg
// (each wave touches only its own 64 rows; 16B/lane = 16 rows x 64B runs).
// W_hi/W_lo: [N][K] bf16 row-major, staged to LDS (32/16 KB) with T2 XOR-swizzle:
//   LDS[row][c] = G[row][ ((c>>3) ^ (row&7))*8 + (c&7) ]   (conflict-free b128 reads)
// Tile: 128 x (NF*32), BK=64, 4 waves of 64 x (NF*16), mfma_f32_16x16x32_bf16,
// 3-term split (ah*wh + ah*wl + al*wh).
// EPI: 0 none, 1 +bias, 3 combined dt+BC (col<1024: softplus(v+bias)->C stride 1024;
//      1024<=col<1056: raw ->C2 stride 32; col>=1056: discard)
template<int EPI, int NF>
__global__ __launch_bounds__(256, 4)
void gemm_mfma(const bf16_t* __restrict__ Ah, const bf16_t* __restrict__ Al,
               const bf16_t* __restrict__ Wh, const bf16_t* __restrict__ Wl,
               const float* __restrict__ bias, float* __restrict__ C,
               float* __restrict__ C2, int M, int N, int K)
{
    constexpr int BN = NF * 32;
    __shared__ bf16_t sm[2 * BN * 64];   // Wh | Wl tiles
    const int tid = threadIdx.x;
    const int w   = tid >> 6;
    const int l   = tid & 63;
    const int m0  = blockIdx.y * 128;
    const int n0  = blockIdx.x * BN;

    const bf16_t* gw0 = Wh + (size_t)n0 * K;
    const bf16_t* gw1 = Wl + (size_t)n0 * K;

    const int srow = l >> 3;                         // staging row within 8-row chunk
    const int scol = ((l & 7) ^ (l >> 3)) * 8;       // swizzled source col (elements)

    const int wm = (w >> 1) * 64;
    const int wn = (w & 1) * (NF * 16);
    const int lr = l & 15;
    const int lk = (l >> 4) * 8;
    const int csw = (l & 7) << 3;                    // read-side XOR (elements)

    // per-lane A row pointers (rows m0+wm+f*16+lr <= 8063 < MPAD always)
    const bf16_t* aph[4];
    const bf16_t* apl[4];
    #pragma unroll
    for (int f = 0; f < 4; ++f) {
        const int r = m0 + wm + f * 16 + lr;
        aph[f] = Ah + (size_t)r * K + lk;
        apl[f] = Al + (size_t)r * K + lk;
    }

    f32x4 acc[4][NF];
    #pragma unroll
    for (int i = 0; i < 4; ++i)
        #pragma unroll
        for (int j = 0; j < NF; ++j) acc[i][j] = (f32x4){0.f,0.f,0.f,0.f};

    for (int kt = 0; kt < K; kt += 64) {
        // stage Wh|Wl tiles: BN/32 chunk-pairs per wave, 1KB each, linear dest
        #pragma unroll
        for (int i = 0; i < BN / 32; ++i) {
            const int lc = (i << 2) | w;
            const size_t go = (size_t)(lc * 8 + srow) * K + kt + scol;
            GL2LDS(gw0 + go, sm + lc * 512);
            GL2LDS(gw1 + go, sm + BN * 64 + lc * 512);
        }
        __syncthreads();
        #pragma unroll
        for (int ks = 0; ks < 2; ++ks) {
            bf16x8 ah[4], al[4], wh[NF], wl[NF];
            const int ko = kt + ks * 32;
            #pragma unroll
            for (int f = 0; f < 4; ++f) {
                ah[f] = *(const bf16x8*)(aph[f] + ko);
                al[f] = *(const bf16x8*)(apl[f] + ko);
            }
            const int koff = (ks * 32 + lk) ^ csw;
            #pragma unroll
            for (int f = 0; f < NF; ++f) {
                const int wr = wn + f * 16 + lr;
                wh[f] = *(const bf16x8*)(sm + wr * 64 + koff);
                wl[f] = *(const bf16x8*)(sm + BN * 64 + wr * 64 + koff);
            }
            #pragma unroll
            for (int fi = 0; fi < 4; ++fi)
                #pragma unroll
                for (int fj = 0; fj < NF; ++fj) {
                    acc[fi][fj] = __builtin_amdgcn_mfma_f32_16x16x32_bf16(ah[fi], wh[fj], acc[fi][fj], 0, 0, 0);
                    acc[fi][fj] = __builtin_amdgcn_mfma_f32_16x16x32_bf16(ah[fi], wl[fj], acc[fi][fj], 0, 0, 0);
                    acc[fi][fj] = __builtin_amdgcn_mfma_f32_16x16x32_bf16(al[fi], wh[fj], acc[fi][fj], 0, 0, 0);
                }
        }
        __syncthreads();
    }
    // epilogue: C/D layout col=lane&15, row=(lane>>4)*4+reg  [m89/m91]
    const int r4 = (l >> 4) * 4;
    #pragma unroll
    for (int fj = 0; fj < NF; ++fj) {
        const int col = n0 + wn + fj * 16 + lr;
        if (EPI == 3 && col >= 1056) continue;
        const float bv = (EPI == 1) ? bias[col]
                       : (EPI == 3 ? (col < 1024 ? bias[col] : 0.f) : 0.f);
        #pragma unroll
        for (int fi = 0; fi < 4; ++fi) {
            const int rowb = m0 + wm + fi * 16 + r4;
            #pragma unroll
            for (int r = 0; r < 4; ++r) {
                const int row = rowb + r;
                if (row >= M) continue;
                float v = acc[fi][fj][r] + bv;
                if (EPI == 3) {
                    if (col < 1024) {
                        v = fmaxf(v, 0.f) + log1pf(__expf(-fabsf(v)));  // softplus
                        C[(size_t)row * 1024 + col] = v;
                    } else {
                        C2[(size_t)row * 32 + (col - 1024)] = v;
                    }
                } else {
                    C[(size_t)row * N + col] = v;
                }
            }
        }
    }
}

// ================= compose W_eff = dt_w @ xproj_w[:32]  (-> bf16 hi/lo) =====
__global__ __launch_bounds__(256)
void compose_dtw(const float* __restrict__ dtw,   // [1024][32]
                 const float* __restrict__ xp,    // [64][1024], rows 0..31 used
                 bf16_t* __restrict__ wh, bf16_t* __restrict__ wl)  // rows 0..1023 of [1152][1024]
{
    const int d0 = blockIdx.x * 4;   // 256 blocks
    const int t  = threadIdx.x;
    float acc[4][4] = {{0.f}};
    for (int r = 0; r < 32; ++r) {
        float xv[4];
        #pragma unroll
        for (int cc = 0; cc < 4; ++cc) xv[cc] = xp[r * 1024 + t + cc * 256];
        #pragma unroll
        for (int dd = 0; dd < 4; ++dd) {
            float wv = dtw[(d0 + dd) * 32 + r];
            #pragma unroll
            for (int cc = 0; cc < 4; ++cc) acc[dd][cc] = fmaf(wv, xv[cc], acc[dd][cc]);
        }
    }
    #pragma unroll
    for (int dd = 0; dd < 4; ++dd)
        #pragma unroll
        for (int cc = 0; cc < 4; ++cc) {
            float v = acc[dd][cc];
            bf16_t hb = (bf16_t)v;
            size_t o = (size_t)(d0 + dd) * 1024 + t + cc * 256;
            wh[o] = hb;
            wl[o] = (bf16_t)(v - (float)hb);
        }
}

// ================= LayerNorm (+res) emitting fp32 + bf16 hi/lo ==============
__global__ __launch_bounds__(256)
void ln_kernel(const float* __restrict__ in, const float* __restrict__ res,
               const float* __restrict__ g, const float* __restrict__ b,
               float* __restrict__ out, bf16_t* __restrict__ oh, bf16_t* __restrict__ ol)
{
    const int lane = threadIdx.x & 63;
    const int wv = threadIdx.x >> 6;
    const int row = blockIdx.x * 4 + wv;
    const size_t base = (size_t)row * EDIM + lane * 8;
    float x[8];
    float4 v0 = *(const float4*)(in + base);
    float4 v1 = *(const float4*)(in + base + 4);
    x[0]=v0.x; x[1]=v0.y; x[2]=v0.z; x[3]=v0.w;
    x[4]=v1.x; x[5]=v1.y; x[6]=v1.z; x[7]=v1.w;
    if (res) {
        float4 r0 = *(const float4*)(res + base);
        float4 r1 = *(const float4*)(res + base + 4);
        x[0]+=r0.x; x[1]+=r0.y; x[2]+=r0.z; x[3]+=r0.w;
        x[4]+=r1.x; x[5]+=r1.y; x[6]+=r1.z; x[7]+=r1.w;
    }
    float s = 0.f, sq = 0.f;
    #pragma unroll
    for (int j = 0; j < 8; ++j) { s += x[j]; sq += x[j]*x[j]; }
    #pragma unroll
    for (int off = 32; off; off >>= 1) {
        s  += __shfl_xor(s, off);
        sq += __shfl_xor(sq, off);
    }
    float mu = s * (1.f/EDIM);
    float var = sq * (1.f/EDIM) - mu*mu;
    float rs = rsqrtf(var + 1e-5f);
    const int col = lane * 8;
    float o[8];
    bf16x8 vh, vl;
    #pragma unroll
    for (int j = 0; j < 8; ++j) {
        o[j] = (x[j] - mu) * rs * g[col+j] + b[col+j];
        bf16_t hb = (bf16_t)o[j];
        vh[j] = hb;
        vl[j] = (bf16_t)(o[j] - (float)hb);
    }
    *(float4*)(out + base)     = make_float4(o[0],o[1],o[2],o[3]);
    *(float4*)(out + base + 4) = make_float4(o[4],o[5],o[6],o[7]);
    *(bf16x8*)(oh + base) = vh;
    *(bf16x8*)(ol + base) = vl;
}

// ======= depthwise causal conv (DC=4) + SiLU, emits bf16 hi/lo ==============
__global__ __launch_bounds__(256)
void conv_silu_k(const float* __restrict__ xz, const float* __restrict__ w,
                 const float* __restrict__ b, bf16_t* __restrict__ xch,
                 bf16_t* __restrict__ xcl)
{
    const int d  = blockIdx.x * 256 + threadIdx.x;  // 0..1023
    const int lc = blockIdx.y;                      // 0..4
    const int n  = blockIdx.z;                      // 0..15
    const int l0 = lc * 100;
    const float w0 = w[d*4+0], w1 = w[d*4+1], w2 = w[d*4+2], w3 = w[d*4+3];
    const float bb = b[d];
    const float* xp = xz + (size_t)n * CHK * 2048 + d;
    float x0 = (l0-3) >= 0 ? xp[(size_t)(l0-3)*2048] : 0.f;
    float x1 = (l0-2) >= 0 ? xp[(size_t)(l0-2)*2048] : 0.f;
    float x2 = (l0-1) >= 0 ? xp[(size_t)(l0-1)*2048] : 0.f;
    const size_t ob = ((size_t)n*CHK + l0) * DI_ + d;
    for (int l = 0; l < 100; ++l) {
        float x3 = xp[(size_t)(l0+l)*2048];
        float v = fmaf(w3,x3, fmaf(w2,x2, fmaf(w1,x1, fmaf(w0,x0, bb))));
        float sv = v / (1.f + __expf(-v));
        bf16_t hv = (bf16_t)sv;
        xch[ob + (size_t)l*DI_] = hv;
        xcl[ob + (size_t)l*DI_] = (bf16_t)(sv - (float)hv);
        x0 = x1; x1 = x2; x2 = x3;
    }
}

// ================= segmented selective scan (3 phases) ======================
__global__ __launch_bounds__(256)
void sc_part(const float* __restrict__ dt, const bf16_t* __restrict__ xch,
             const bf16_t* __restrict__ xcl, const float* __restrict__ bc,
             const float* __restrict__ Alog,
             float* __restrict__ pA, float* __restrict__ loc)
{
    __shared__ float Bs[LSEG][SDIM];
    const int d  = blockIdx.x * 256 + threadIdx.x;
    const int n  = blockIdx.y;
    const int sg = blockIdx.z;
    const int t0 = sg * LSEG;
    const size_t rb = (size_t)n*CHK + t0;
    for (int idx = threadIdx.x; idx < LSEG*SDIM; idx += 256) {
        int t = idx >> 4, s = idx & 15;
        Bs[t][s] = bc[(rb + t)*32 + s];
    }
    __syncthreads();
    float A[SDIM], p[SDIM], lcl[SDIM];
    #pragma unroll
    for (int s = 0; s < SDIM; ++s) {
        A[s] = -__expf(Alog[d*SDIM + s]); p[s] = 1.f; lcl[s] = 0.f;
    }
    for (int t = 0; t < LSEG; ++t) {
        float dtv = dt[(rb+t)*DI_ + d];
        float xv  = (float)xch[(rb+t)*DI_ + d] + (float)xcl[(rb+t)*DI_ + d];
        float dx = dtv * xv;
        #pragma unroll
        for (int s = 0; s < SDIM; ++s) {
            float dA = __expf(dtv * A[s]);
            p[s] *= dA;
            lcl[s] = fmaf(dA, lcl[s], dx * Bs[t][s]);
        }
    }
    const size_t ob = ((size_t)(n*PSEG + sg) << 14) + d*16;
    #pragma unroll
    for (int s = 0; s < SDIM; s += 4) {
        *(float4*)(pA  + ob + s) = make_float4(p[s],p[s+1],p[s+2],p[s+3]);
        *(float4*)(loc + ob + s) = make_float4(lcl[s],lcl[s+1],lcl[s+2],lcl[s+3]);
    }
}

__global__ __launch_bounds__(256)
void sc_comb(const float* __restrict__ pA, float* __restrict__ hio)
{
    const int gI = blockIdx.x * 256 + threadIdx.x;   // 0..262143
    const int n = gI >> 14;
    const int r = gI & 16383;
    float h = 0.f;
    #pragma unroll
    for (int sg = 0; sg < PSEG; ++sg) {
        size_t idx = ((size_t)(n*PSEG + sg) << 14) + r;
        float pa = pA[idx];
        float lo = hio[idx];
        hio[idx] = h;
        h = fmaf(pa, h, lo);
    }
}

__global__ __launch_bounds__(256)
void sc_fin(const float* __restrict__ dt, const bf16_t* __restrict__ xch,
            const bf16_t* __restrict__ xcl, const float* __restrict__ xz,
            const float* __restrict__ bc, const float* __restrict__ Alog,
            const float* __restrict__ Dp, const float* __restrict__ hin,
            bf16_t* __restrict__ yh, bf16_t* __restrict__ yl)
{
    __shared__ float BCs[LSEG][32];
    const int d  = blockIdx.x * 256 + threadIdx.x;
    const int n  = blockIdx.y;
    const int sg = blockIdx.z;
    const int t0 = sg * LSEG;
    const size_t rb = (size_t)n*CHK + t0;
    for (int idx = threadIdx.x; idx < LSEG*32; idx += 256) {
        int t = idx >> 5, s = idx & 31;
        BCs[t][s] = bc[(rb + t)*32 + s];
    }
    __syncthreads();
    float A[SDIM], h[SDIM];
    #pragma unroll
    for (int s = 0; s < SDIM; ++s) A[s] = -__expf(Alog[d*SDIM + s]);
    const size_t hb = ((size_t)(n*PSEG + sg) << 14) + d*16;
    #pragma unroll
    for (int s = 0; s < SDIM; ++s) h[s] = hin[hb + s];
    const float Dv = Dp[d];
    for (int t = 0; t < LSEG; ++t) {
        const size_t p = rb + t;
        float dtv = dt[p*DI_ + d];
        float xv  = (float)xch[p*DI_ + d] + (float)xcl[p*DI_ + d];
        float zv  = xz[p*2048 + DI_ + d];
        float dx = dtv * xv;
        float accv = 0.f;
        #pragma unroll
        for (int s = 0; s < SDIM; ++s) {
            float dA = __expf(dtv * A[s]);
            h[s] = fmaf(dA, h[s], dx * BCs[t][s]);
            accv = fmaf(h[s], BCs[t][16+s], accv);
        }
        float yv = fmaf(xv, Dv, accv);
        float sz = zv / (1.f + __expf(-zv));
        float outv = yv * sz;
        bf16_t oh = (bf16_t)outv;
        yh[p*DI_ + d] = oh;
        yl[p*DI_ + d] = (bf16_t)(outv - (float)oh);
    }
}

// ================= fp32 -> bf16 hi/lo split (pad region zeroed) =============
__global__ __launch_bounds__(256)
void convert_split(const float* __restrict__ src, bf16_t* __restrict__ hi,
                   bf16_t* __restrict__ lo, long n, long valid)
{
    long i = ((long)blockIdx.x * 256 + threadIdx.x) * 4;
    if (i >= n) return;
    float4 v = make_float4(0.f,0.f,0.f,0.f);
    if (i < valid) v = *(const float4*)(src + i);
    float a[4] = {v.x, v.y, v.z, v.w};
    bf16x4 vh, vl;
    #pragma unroll
    for (int j = 0; j < 4; ++j) {
        bf16_t hb = (bf16_t)a[j];
        vh[j] = hb;
        vl[j] = (bf16_t)(a[j] - (float)hb);
    }
    *(bf16x4*)(hi + i) = vh;
    *(bf16x4*)(lo + i) = vl;
}

// ============================================================================
extern "C" void kernel_launch(void* const* d_in, const int* in_sizes, int n_in,
                              void* d_out, int out_size, void* d_ws, size_t ws_size,
                              hipStream_t stream) {
    (void)in_sizes; (void)n_in; (void)out_size; (void)ws_size;
    const float* sf       = (const float*)d_in[0];
    const float* ip_w     = (const float*)d_in[1];
    const float* ip_b     = (const float*)d_in[2];
    const float* ilng     = (const float*)d_in[3];
    const float* ilnb     = (const float*)d_in[4];
    const float* m_in_w   = (const float*)d_in[5];
    const float* m_conv_w = (const float*)d_in[6];
    const float* m_conv_b = (const float*)d_in[7];
    const float* m_xproj_w= (const float*)d_in[8];
    const float* m_dt_w   = (const float*)d_in[9];
    const float* m_dt_b   = (const float*)d_in[10];
    const float* m_Alog   = (const float*)d_in[11];
    const float* m_D      = (const float*)d_in[12];
    const float* m_out_w  = (const float*)d_in[13];
    const float* ln_g     = (const float*)d_in[14];
    const float* ln_b     = (const float*)d_in[15];
    const float* op_w     = (const float*)d_in[16];
    const float* op_b     = (const float*)d_in[17];
    float* outp = (float*)d_out;

    // -------- workspace layout (fp32 part) --------
    float* t0   = (float*)d_ws;                    // 8000*512
    float* h    = t0   + 4096000;                  // 8000*512
    float* xzb  = h    + 4096000;                  // 8000*2048
    float* dtb  = xzb  + 16384000;                 // 8000*1024
    float* bcb  = dtb  + 8192000;                  // 8000*32
    float* pAb  = bcb  + 256000;                   // 16*10*1024*16
    float* locb = pAb  + 2621440;                  // 16*10*1024*16
    // -------- bf16 part --------
    bf16_t* hh  = (bf16_t*)(locb + 2621440);       // 8064*512
    bf16_t* hl  = hh  + 4128768;
    bf16_t* xch = hl  + 4128768;                   // 8064*1024
    bf16_t* xcl = xch + 8257536;
    bf16_t* yh  = xcl + 8257536;                   // 8064*1024
    bf16_t* yl  = yh  + 8257536;
    bf16_t* sfh = yh;                              // alias: sf lifetime ends before yh written
    bf16_t* sfl = yl;
    bf16_t* wiph = yl + 8257536;                   // 512*512
    bf16_t* wipl = wiph + 262144;
    bf16_t* winh = wipl + 262144;                  // 2*2048*512
    bf16_t* winl = winh + 2097152;
    bf16_t* wouth= winl + 2097152;                 // 2*512*1024
    bf16_t* woutl= wouth + 1048576;
    bf16_t* woph = woutl + 1048576;                // 512*512
    bf16_t* wopl = woph + 262144;
    bf16_t* wcmbh= wopl + 262144;                  // 1152*1024 (per-layer, reused)
    bf16_t* wcmbl= wcmbh + 1179648;

    dim3 blk(256);
    // -------- weight + input conversions --------
    convert_split<<<256,  blk, 0, stream>>>(ip_w,    wiph, wipl, 262144,  262144);
    convert_split<<<2048, blk, 0, stream>>>(m_in_w,  winh, winl, 2097152, 2097152);
    convert_split<<<1024, blk, 0, stream>>>(m_out_w, wouth,woutl,1048576, 1048576);
    convert_split<<<256,  blk, 0, stream>>>(op_w,    woph, wopl, 262144,  262144);
    convert_split<<<4032, blk, 0, stream>>>(sf,      sfh,  sfl,  4128768, 4096000);

    // -------- input projection + LN --------
    gemm_mfma<1,2><<<dim3(8,63), blk, 0, stream>>>(sfh, sfl, wiph, wipl, ip_b, t0, nullptr, NSL, EDIM, 512);
    ln_kernel<<<2000, blk, 0, stream>>>(t0, nullptr, ilng, ilnb, h, hh, hl);

    for (int l = 0; l < NLAY; ++l) {
        const float* xp_l  = m_xproj_w + (size_t)l * 64 * 1024;   // 64 rows/layer
        // xz = h @ in_w^T   [8000,512] x [2048,512]^T
        gemm_mfma<0,4><<<dim3(16,63), blk, 0, stream>>>(hh, hl, winh + (size_t)l*1048576, winl + (size_t)l*1048576,
                                                        nullptr, xzb, nullptr, NSL, 2048, EDIM);
        // depthwise conv + silu -> xc (bf16 hi/lo)
        conv_silu_k<<<dim3(4,5,16), blk, 0, stream>>>(xzb, m_conv_w + (size_t)l*DI_*4, m_conv_b + (size_t)l*DI_, xch, xcl);
        // build combined weight: rows 0..1023 = dt_w @ xproj[:32]; rows 1024..1055 = xproj[32:64]
        compose_dtw<<<256, blk, 0, stream>>>(m_dt_w + (size_t)l*DI_*32, xp_l, wcmbh, wcmbl);
        convert_split<<<32, blk, 0, stream>>>(xp_l + 32*1024, wcmbh + 1048576, wcmbl + 1048576, 32768, 32768);
        // dt (softplus, cols 0..1023) + BC (cols 1024..1055) in one MFMA GEMM
        gemm_mfma<3,4><<<dim3(9,63), blk, 0, stream>>>(xch, xcl, wcmbh, wcmbl, m_dt_b + (size_t)l*DI_,
                                                       dtb, bcb, NSL, 1152, 1024);
        // segmented scan
        sc_part<<<dim3(4,16,PSEG), blk, 0, stream>>>(dtb, xch, xcl, bcb, m_Alog + (size_t)l*DI_*SDIM, pAb, locb);
        sc_comb<<<1024, blk, 0, stream>>>(pAb, locb);
        sc_fin<<<dim3(4,16,PSEG), blk, 0, stream>>>(dtb, xch, xcl, xzb, bcb, m_Alog + (size_t)l*DI_*SDIM,
                                                    m_D + (size_t)l*DI_, locb, yh, yl);
        // mamba out proj  [8000,1024] x [512,1024]^T
        gemm_mfma<0,2><<<dim3(8,63), blk, 0, stream>>>(yh, yl, wouth + (size_t)l*524288, woutl + (size_t)l*524288,
                                                       nullptr, t0, nullptr, NSL, EDIM, DI_);
        // h = LN(mamba_out + h), emit bf16 hi/lo
        ln_kernel<<<2000, blk, 0, stream>>>(t0, h, ln_g + (size_t)l*EDIM, ln_b + (size_t)l*EDIM, h, hh, hl);
    }
    // final projection (fp32 out with bias)
    gemm_mfma<1,2><<<dim3(8,63), blk, 0, stream>>>(hh, hl, woph, wopl, op_b, outp, nullptr, NSL, EDIM, 512);
}

// Round 10
// 918.786 us; speedup vs baseline: 1.5314x; 1.5314x over previous
//
#include <hip/hip_runtime.h>
#include <hip/hip_bf16.h>
#include <math.h>

// Problem constants
#define NSL 8000
#define MPAD 8064          // 63 * 128
#define EDIM 512
#define DI_ 1024
#define SDIM 16
#define NLAY 2
#define CHK 500
#define PSEG 10
#define LSEG 50

typedef __bf16 bf16_t;
typedef bf16_t bf16x8 __attribute__((ext_vector_type(8)));
typedef bf16_t bf16x4 __attribute__((ext_vector_type(4)));
typedef float  f32x4  __attribute__((ext_vector_type(4)));

#define GL2LDS(g, l) __builtin_amdgcn_global_load_lds( \
    (const __attribute__((address_space(1))) void*)(g), \
    (__attribute__((address_space(3))) void*)(l), 16, 0, 0)

// ================= split-bf16 MFMA GEMM: C = A*W^T (+epilogue) =================
// BK=32, 128x128 output tile, 4 waves of 64x64, 32 KB LDS total.
// LDS layout: 2 combined tiles [128 rows][64 bf16]; each 128B row = [hi 32 | lo 32],
// XOR-swizzled in 16B slots: physical slot p at row r holds global slot p^(r&7).
// Staging: global_load_lds with PER-LANE source (slot<4 -> *_hi, else *_lo base),
// linear LDS dest (wave-uniform base + lane*16B).  [verified pattern: r6 conflicts=0]
// 3-term split: ah*wh + ah*wl + al*wh.
// EPI: 0 none, 1 +bias, 3 combined dt+BC (col<1024: softplus(v+bias)->C stride 1024;
//      1024<=col<1056: raw ->C2 stride 32; col>=1056: discard)
template<int EPI>
__global__ __launch_bounds__(256, 4)
void gemm_mfma(const bf16_t* __restrict__ Ah, const bf16_t* __restrict__ Al,
               const bf16_t* __restrict__ Wh, const bf16_t* __restrict__ Wl,
               const float* __restrict__ bias, float* __restrict__ C,
               float* __restrict__ C2, int M, int N, int K)
{
    __shared__ bf16_t sm[2 * 128 * 64];   // A-combined | W-combined, 32 KB
    const int tid = threadIdx.x;
    const int w   = tid >> 6;
    const int l   = tid & 63;
    const int m0  = blockIdx.y * 128;
    const int n0  = blockIdx.x * 128;

    // ---- staging geometry (per gload_lds: 8 combined rows, lane l -> row l>>3, slot l&7)
    const int srow  = l >> 3;                 // row within 8-row chunk
    const int sslot = (l & 7) ^ srow;         // swizzled GLOBAL slot for this lane
    const int sc    = sslot * 8;              // global combined col (elements), 0..56
    const bf16_t* asrc[4];
    const bf16_t* wsrc[4];
    #pragma unroll
    for (int i = 0; i < 4; ++i) {
        const int lc  = (i << 2) | w;         // chunk 0..15 (wave-uniform dest base)
        const int row = lc * 8 + srow;
        asrc[i] = (sc < 32) ? Ah + (size_t)(m0 + row) * K + sc
                            : Al + (size_t)(m0 + row) * K + (sc - 32);
        wsrc[i] = (sc < 32) ? Wh + (size_t)(n0 + row) * K + sc
                            : Wl + (size_t)(n0 + row) * K + (sc - 32);
    }

    // ---- fragment-read geometry
    const int wm  = (w >> 1) * 64;
    const int wn  = (w & 1) * 64;
    const int lr  = l & 15;
    const int lk  = (l >> 4) * 8;             // k-slice within BK=32
    const int csw = (l & 7) << 3;             // (row&7)<<3 == (l&7)<<3 for all our rows
    const int cHi = lk ^ csw;                 // physical col of hi fragment
    const int cLo = (32 + lk) ^ csw;          // physical col of lo fragment

    f32x4 acc[4][4];
    #pragma unroll
    for (int i = 0; i < 4; ++i)
        #pragma unroll
        for (int j = 0; j < 4; ++j) acc[i][j] = (f32x4){0.f,0.f,0.f,0.f};

    for (int kt = 0; kt < K; kt += 32) {
        #pragma unroll
        for (int i = 0; i < 4; ++i) {
            const int lc = (i << 2) | w;
            GL2LDS(asrc[i] + kt, sm + lc * 512);           // A combined tile
            GL2LDS(wsrc[i] + kt, sm + 8192 + lc * 512);    // W combined tile
        }
        __syncthreads();
        bf16x8 ah[4], al[4], wh[4], wl[4];
        #pragma unroll
        for (int f = 0; f < 4; ++f) {
            const int ar = (wm + f * 16 + lr) * 64;
            const int wr = (wn + f * 16 + lr) * 64;
            ah[f] = *(const bf16x8*)(sm + ar + cHi);
            al[f] = *(const bf16x8*)(sm + ar + cLo);
            wh[f] = *(const bf16x8*)(sm + 8192 + wr + cHi);
            wl[f] = *(const bf16x8*)(sm + 8192 + wr + cLo);
        }
        #pragma unroll
        for (int fi = 0; fi < 4; ++fi)
            #pragma unroll
            for (int fj = 0; fj < 4; ++fj) {
                acc[fi][fj] = __builtin_amdgcn_mfma_f32_16x16x32_bf16(ah[fi], wh[fj], acc[fi][fj], 0, 0, 0);
                acc[fi][fj] = __builtin_amdgcn_mfma_f32_16x16x32_bf16(ah[fi], wl[fj], acc[fi][fj], 0, 0, 0);
                acc[fi][fj] = __builtin_amdgcn_mfma_f32_16x16x32_bf16(al[fi], wh[fj], acc[fi][fj], 0, 0, 0);
            }
        __syncthreads();
    }
    // epilogue: C/D layout col=lane&15, row=(lane>>4)*4+reg  [m89/m91]
    const int r4 = (l >> 4) * 4;
    #pragma unroll
    for (int fj = 0; fj < 4; ++fj) {
        const int col = n0 + wn + fj * 16 + lr;
        if (EPI == 3 && col >= 1056) continue;
        const float bv = (EPI == 1) ? bias[col]
                       : (EPI == 3 ? (col < 1024 ? bias[col] : 0.f) : 0.f);
        #pragma unroll
        for (int fi = 0; fi < 4; ++fi) {
            const int rowb = m0 + wm + fi * 16 + r4;
            #pragma unroll
            for (int r = 0; r < 4; ++r) {
                const int row = rowb + r;
                if (row >= M) continue;
                float v = acc[fi][fj][r] + bv;
                if (EPI == 3) {
                    if (col < 1024) {
                        v = fmaxf(v, 0.f) + log1pf(__expf(-fabsf(v)));  // softplus
                        C[(size_t)row * 1024 + col] = v;
                    } else {
                        C2[(size_t)row * 32 + (col - 1024)] = v;
                    }
                } else {
                    C[(size_t)row * N + col] = v;
                }
            }
        }
    }
}

// ================= compose W_eff = dt_w @ xproj_w[:32]  (-> bf16 hi/lo) =====
__global__ __launch_bounds__(256)
void compose_dtw(const float* __restrict__ dtw,   // [1024][32]
                 const float* __restrict__ xp,    // [64][1024], rows 0..31 used
                 bf16_t* __restrict__ wh, bf16_t* __restrict__ wl)  // rows 0..1023 of [1152][1024]
{
    const int d0 = blockIdx.x * 4;   // 256 blocks
    const int t  = threadIdx.x;
    float acc[4][4] = {{0.f}};
    for (int r = 0; r < 32; ++r) {
        float xv[4];
        #pragma unroll
        for (int cc = 0; cc < 4; ++cc) xv[cc] = xp[r * 1024 + t + cc * 256];
        #pragma unroll
        for (int dd = 0; dd < 4; ++dd) {
            float wv = dtw[(d0 + dd) * 32 + r];
            #pragma unroll
            for (int cc = 0; cc < 4; ++cc) acc[dd][cc] = fmaf(wv, xv[cc], acc[dd][cc]);
        }
    }
    #pragma unroll
    for (int dd = 0; dd < 4; ++dd)
        #pragma unroll
        for (int cc = 0; cc < 4; ++cc) {
            float v = acc[dd][cc];
            bf16_t hb = (bf16_t)v;
            size_t o = (size_t)(d0 + dd) * 1024 + t + cc * 256;
            wh[o] = hb;
            wl[o] = (bf16_t)(v - (float)hb);
        }
}

// ================= LayerNorm (+res) emitting fp32 + bf16 hi/lo ==============
__global__ __launch_bounds__(256)
void ln_kernel(const float* __restrict__ in, const float* __restrict__ res,
               const float* __restrict__ g, const float* __restrict__ b,
               float* __restrict__ out, bf16_t* __restrict__ oh, bf16_t* __restrict__ ol)
{
    const int lane = threadIdx.x & 63;
    const int wv = threadIdx.x >> 6;
    const int row = blockIdx.x * 4 + wv;
    const size_t base = (size_t)row * EDIM + lane * 8;
    float x[8];
    float4 v0 = *(const float4*)(in + base);
    float4 v1 = *(const float4*)(in + base + 4);
    x[0]=v0.x; x[1]=v0.y; x[2]=v0.z; x[3]=v0.w;
    x[4]=v1.x; x[5]=v1.y; x[6]=v1.z; x[7]=v1.w;
    if (res) {
        float4 r0 = *(const float4*)(res + base);
        float4 r1 = *(const float4*)(res + base + 4);
        x[0]+=r0.x; x[1]+=r0.y; x[2]+=r0.z; x[3]+=r0.w;
        x[4]+=r1.x; x[5]+=r1.y; x[6]+=r1.z; x[7]+=r1.w;
    }
    float s = 0.f, sq = 0.f;
    #pragma unroll
    for (int j = 0; j < 8; ++j) { s += x[j]; sq += x[j]*x[j]; }
    #pragma unroll
    for (int off = 32; off; off >>= 1) {
        s  += __shfl_xor(s, off);
        sq += __shfl_xor(sq, off);
    }
    float mu = s * (1.f/EDIM);
    float var = sq * (1.f/EDIM) - mu*mu;
    float rs = rsqrtf(var + 1e-5f);
    const int col = lane * 8;
    float o[8];
    bf16x8 vh, vl;
    #pragma unroll
    for (int j = 0; j < 8; ++j) {
        o[j] = (x[j] - mu) * rs * g[col+j] + b[col+j];
        bf16_t hb = (bf16_t)o[j];
        vh[j] = hb;
        vl[j] = (bf16_t)(o[j] - (float)hb);
    }
    *(float4*)(out + base)     = make_float4(o[0],o[1],o[2],o[3]);
    *(float4*)(out + base + 4) = make_float4(o[4],o[5],o[6],o[7]);
    *(bf16x8*)(oh + base) = vh;
    *(bf16x8*)(ol + base) = vl;
}

// ======= depthwise causal conv (DC=4) + SiLU, emits bf16 hi/lo ==============
__global__ __launch_bounds__(256)
void conv_silu_k(const float* __restrict__ xz, const float* __restrict__ w,
                 const float* __restrict__ b, bf16_t* __restrict__ xch,
                 bf16_t* __restrict__ xcl)
{
    const int d  = blockIdx.x * 256 + threadIdx.x;  // 0..1023
    const int lc = blockIdx.y;                      // 0..4
    const int n  = blockIdx.z;                      // 0..15
    const int l0 = lc * 100;
    const float w0 = w[d*4+0], w1 = w[d*4+1], w2 = w[d*4+2], w3 = w[d*4+3];
    const float bb = b[d];
    const float* xp = xz + (size_t)n * CHK * 2048 + d;
    float x0 = (l0-3) >= 0 ? xp[(size_t)(l0-3)*2048] : 0.f;
    float x1 = (l0-2) >= 0 ? xp[(size_t)(l0-2)*2048] : 0.f;
    float x2 = (l0-1) >= 0 ? xp[(size_t)(l0-1)*2048] : 0.f;
    const size_t ob = ((size_t)n*CHK + l0) * DI_ + d;
    for (int l = 0; l < 100; ++l) {
        float x3 = xp[(size_t)(l0+l)*2048];
        float v = fmaf(w3,x3, fmaf(w2,x2, fmaf(w1,x1, fmaf(w0,x0, bb))));
        float sv = v / (1.f + __expf(-v));
        bf16_t hv = (bf16_t)sv;
        xch[ob + (size_t)l*DI_] = hv;
        xcl[ob + (size_t)l*DI_] = (bf16_t)(sv - (float)hv);
        x0 = x1; x1 = x2; x2 = x3;
    }
}

// ================= segmented selective scan (3 phases) ======================
__global__ __launch_bounds__(256)
void sc_part(const float* __restrict__ dt, const bf16_t* __restrict__ xch,
             const bf16_t* __restrict__ xcl, const float* __restrict__ bc,
             const float* __restrict__ Alog,
             float* __restrict__ pA, float* __restrict__ loc)
{
    __shared__ float Bs[LSEG][SDIM];
    const int d  = blockIdx.x * 256 + threadIdx.x;
    const int n  = blockIdx.y;
    const int sg = blockIdx.z;
    const int t0 = sg * LSEG;
    const size_t rb = (size_t)n*CHK + t0;
    for (int idx = threadIdx.x; idx < LSEG*SDIM; idx += 256) {
        int t = idx >> 4, s = idx & 15;
        Bs[t][s] = bc[(rb + t)*32 + s];
    }
    __syncthreads();
    float A[SDIM], p[SDIM], lcl[SDIM];
    #pragma unroll
    for (int s = 0; s < SDIM; ++s) {
        A[s] = -__expf(Alog[d*SDIM + s]); p[s] = 1.f; lcl[s] = 0.f;
    }
    for (int t = 0; t < LSEG; ++t) {
        float dtv = dt[(rb+t)*DI_ + d];
        float xv  = (float)xch[(rb+t)*DI_ + d] + (float)xcl[(rb+t)*DI_ + d];
        float dx = dtv * xv;
        #pragma unroll
        for (int s = 0; s < SDIM; ++s) {
            float dA = __expf(dtv * A[s]);
            p[s] *= dA;
            lcl[s] = fmaf(dA, lcl[s], dx * Bs[t][s]);
        }
    }
    const size_t ob = ((size_t)(n*PSEG + sg) << 14) + d*16;
    #pragma unroll
    for (int s = 0; s < SDIM; s += 4) {
        *(float4*)(pA  + ob + s) = make_float4(p[s],p[s+1],p[s+2],p[s+3]);
        *(float4*)(loc + ob + s) = make_float4(lcl[s],lcl[s+1],lcl[s+2],lcl[s+3]);
    }
}

__global__ __launch_bounds__(256)
void sc_comb(const float* __restrict__ pA, float* __restrict__ hio)
{
    const int gI = blockIdx.x * 256 + threadIdx.x;   // 0..262143
    const int n = gI >> 14;
    const int r = gI & 16383;
    float h = 0.f;
    #pragma unroll
    for (int sg = 0; sg < PSEG; ++sg) {
        size_t idx = ((size_t)(n*PSEG + sg) << 14) + r;
        float pa = pA[idx];
        float lo = hio[idx];
        hio[idx] = h;
        h = fmaf(pa, h, lo);
    }
}

__global__ __launch_bounds__(256)
void sc_fin(const float* __restrict__ dt, const bf16_t* __restrict__ xch,
            const bf16_t* __restrict__ xcl, const float* __restrict__ xz,
            const float* __restrict__ bc, const float* __restrict__ Alog,
            const float* __restrict__ Dp, const float* __restrict__ hin,
            bf16_t* __restrict__ yh, bf16_t* __restrict__ yl)
{
    __shared__ float BCs[LSEG][32];
    const int d  = blockIdx.x * 256 + threadIdx.x;
    const int n  = blockIdx.y;
    const int sg = blockIdx.z;
    const int t0 = sg * LSEG;
    const size_t rb = (size_t)n*CHK + t0;
    for (int idx = threadIdx.x; idx < LSEG*32; idx += 256) {
        int t = idx >> 5, s = idx & 31;
        BCs[t][s] = bc[(rb + t)*32 + s];
    }
    __syncthreads();
    float A[SDIM], h[SDIM];
    #pragma unroll
    for (int s = 0; s < SDIM; ++s) A[s] = -__expf(Alog[d*SDIM + s]);
    const size_t hb = ((size_t)(n*PSEG + sg) << 14) + d*16;
    #pragma unroll
    for (int s = 0; s < SDIM; ++s) h[s] = hin[hb + s];
    const float Dv = Dp[d];
    for (int t = 0; t < LSEG; ++t) {
        const size_t p = rb + t;
        float dtv = dt[p*DI_ + d];
        float xv  = (float)xch[p*DI_ + d] + (float)xcl[p*DI_ + d];
        float zv  = xz[p*2048 + DI_ + d];
        float dx = dtv * xv;
        float accv = 0.f;
        #pragma unroll
        for (int s = 0; s < SDIM; ++s) {
            float dA = __expf(dtv * A[s]);
            h[s] = fmaf(dA, h[s], dx * BCs[t][s]);
            accv = fmaf(h[s], BCs[t][16+s], accv);
        }
        float yv = fmaf(xv, Dv, accv);
        float sz = zv / (1.f + __expf(-zv));
        float outv = yv * sz;
        bf16_t oh = (bf16_t)outv;
        yh[p*DI_ + d] = oh;
        yl[p*DI_ + d] = (bf16_t)(outv - (float)oh);
    }
}

// ================= fp32 -> bf16 hi/lo split (pad region zeroed) =============
__global__ __launch_bounds__(256)
void convert_split(const float* __restrict__ src, bf16_t* __restrict__ hi,
                   bf16_t* __restrict__ lo, long n, long valid)
{
    long i = ((long)blockIdx.x * 256 + threadIdx.x) * 4;
    if (i >= n) return;
    float4 v = make_float4(0.f,0.f,0.f,0.f);
    if (i < valid) v = *(const float4*)(src + i);
    float a[4] = {v.x, v.y, v.z, v.w};
    bf16x4 vh, vl;
    #pragma unroll
    for (int j = 0; j < 4; ++j) {
        bf16_t hb = (bf16_t)a[j];
        vh[j] = hb;
        vl[j] = (bf16_t)(a[j] - (float)hb);
    }
    *(bf16x4*)(hi + i) = vh;
    *(bf16x4*)(lo + i) = vl;
}

// ============================================================================
extern "C" void kernel_launch(void* const* d_in, const int* in_sizes, int n_in,
                              void* d_out, int out_size, void* d_ws, size_t ws_size,
                              hipStream_t stream) {
    (void)in_sizes; (void)n_in; (void)out_size; (void)ws_size;
    const float* sf       = (const float*)d_in[0];
    const float* ip_w     = (const float*)d_in[1];
    const float* ip_b     = (const float*)d_in[2];
    const float* ilng     = (const float*)d_in[3];
    const float* ilnb     = (const float*)d_in[4];
    const float* m_in_w   = (const float*)d_in[5];
    const float* m_conv_w = (const float*)d_in[6];
    const float* m_conv_b = (const float*)d_in[7];
    const float* m_xproj_w= (const float*)d_in[8];
    const float* m_dt_w   = (const float*)d_in[9];
    const float* m_dt_b   = (const float*)d_in[10];
    const float* m_Alog   = (const float*)d_in[11];
    const float* m_D      = (const float*)d_in[12];
    const float* m_out_w  = (const float*)d_in[13];
    const float* ln_g     = (const float*)d_in[14];
    const float* ln_b     = (const float*)d_in[15];
    const float* op_w     = (const float*)d_in[16];
    const float* op_b     = (const float*)d_in[17];
    float* outp = (float*)d_out;

    // -------- workspace layout (fp32 part) --------
    float* t0   = (float*)d_ws;                    // 8000*512
    float* h    = t0   + 4096000;                  // 8000*512
    float* xzb  = h    + 4096000;                  // 8000*2048
    float* dtb  = xzb  + 16384000;                 // 8000*1024
    float* bcb  = dtb  + 8192000;                  // 8000*32
    float* pAb  = bcb  + 256000;                   // 16*10*1024*16
    float* locb = pAb  + 2621440;                  // 16*10*1024*16
    // -------- bf16 part --------
    bf16_t* hh  = (bf16_t*)(locb + 2621440);       // 8064*512
    bf16_t* hl  = hh  + 4128768;
    bf16_t* xch = hl  + 4128768;                   // 8064*1024
    bf16_t* xcl = xch + 8257536;
    bf16_t* yh  = xcl + 8257536;                   // 8064*1024
    bf16_t* yl  = yh  + 8257536;
    bf16_t* sfh = yh;                              // alias: sf lifetime ends before yh written
    bf16_t* sfl = yl;
    bf16_t* wiph = yl + 8257536;                   // 512*512
    bf16_t* wipl = wiph + 262144;
    bf16_t* winh = wipl + 262144;                  // 2*2048*512
    bf16_t* winl = winh + 2097152;
    bf16_t* wouth= winl + 2097152;                 // 2*512*1024
    bf16_t* woutl= wouth + 1048576;
    bf16_t* woph = woutl + 1048576;                // 512*512
    bf16_t* wopl = woph + 262144;
    bf16_t* wcmbh= wopl + 262144;                  // 1152*1024 (per-layer, reused)
    bf16_t* wcmbl= wcmbh + 1179648;

    dim3 blk(256);
    // -------- weight + input conversions --------
    convert_split<<<256,  blk, 0, stream>>>(ip_w,    wiph, wipl, 262144,  262144);
    convert_split<<<2048, blk, 0, stream>>>(m_in_w,  winh, winl, 2097152, 2097152);
    convert_split<<<1024, blk, 0, stream>>>(m_out_w, wouth,woutl,1048576, 1048576);
    convert_split<<<256,  blk, 0, stream>>>(op_w,    woph, wopl, 262144,  262144);
    convert_split<<<4032, blk, 0, stream>>>(sf,      sfh,  sfl,  4128768, 4096000);

    // -------- input projection + LN --------
    gemm_mfma<1><<<dim3(4,63), blk, 0, stream>>>(sfh, sfl, wiph, wipl, ip_b, t0, nullptr, NSL, EDIM, 512);
    ln_kernel<<<2000, blk, 0, stream>>>(t0, nullptr, ilng, ilnb, h, hh, hl);

    for (int l = 0; l < NLAY; ++l) {
        const float* xp_l  = m_xproj_w + (size_t)l * 64 * 1024;   // 64 rows/layer
        // xz = h @ in_w^T   [8000,512] x [2048,512]^T
        gemm_mfma<0><<<dim3(16,63), blk, 0, stream>>>(hh, hl, winh + (size_t)l*1048576, winl + (size_t)l*1048576,
                                                      nullptr, xzb, nullptr, NSL, 2048, EDIM);
        // depthwise conv + silu -> xc (bf16 hi/lo)
        conv_silu_k<<<dim3(4,5,16), blk, 0, stream>>>(xzb, m_conv_w + (size_t)l*DI_*4, m_conv_b + (size_t)l*DI_, xch, xcl);
        // build combined weight: rows 0..1023 = dt_w @ xproj[:32]; rows 1024..1055 = xproj[32:64]
        compose_dtw<<<256, blk, 0, stream>>>(m_dt_w + (size_t)l*DI_*32, xp_l, wcmbh, wcmbl);
        convert_split<<<32, blk, 0, stream>>>(xp_l + 32*1024, wcmbh + 1048576, wcmbl + 1048576, 32768, 32768);
        // dt (softplus, cols 0..1023) + BC (cols 1024..1055) in one MFMA GEMM
        gemm_mfma<3><<<dim3(9,63), blk, 0, stream>>>(xch, xcl, wcmbh, wcmbl, m_dt_b + (size_t)l*DI_,
                                                     dtb, bcb, NSL, 1152, 1024);
        // segmented scan
        sc_part<<<dim3(4,16,PSEG), blk, 0, stream>>>(dtb, xch, xcl, bcb, m_Alog + (size_t)l*DI_*SDIM, pAb, locb);
        sc_comb<<<1024, blk, 0, stream>>>(pAb, locb);
        sc_fin<<<dim3(4,16,PSEG), blk, 0, stream>>>(dtb, xch, xcl, xzb, bcb, m_Alog + (size_t)l*DI_*SDIM,
                                                    m_D + (size_t)l*DI_, locb, yh, yl);
        // mamba out proj  [8000,1024] x [512,1024]^T
        gemm_mfma<0><<<dim3(4,63), blk, 0, stream>>>(yh, yl, wouth + (size_t)l*524288, woutl + (size_t)l*524288,
                                                     nullptr, t0, nullptr, NSL, EDIM, DI_);
        // h = LN(mamba_out + h), emit bf16 hi/lo
        ln_kernel<<<2000, blk, 0, stream>>>(t0, h, ln_g + (size_t)l*EDIM, ln_b + (size_t)l*EDIM, h, hh, hl);
    }
    // final projection (fp32 out with bias)
    gemm_mfma<1><<<dim3(4,63), blk, 0, stream>>>(hh, hl, woph, wopl, op_b, outp, nullptr, NSL, EDIM, 512);
}